// Round 1
// baseline (995.439 us; speedup 1.0000x reference)
//
#include <hip/hip_runtime.h>
#include <math.h>

#define J_LEN 81
#define DIM 128
#define HEADS 4
#define HD 32
#define SCALE 0.17677669529663687f  // (128/4)^-0.5 = 1/sqrt(32)

__global__ __launch_bounds__(256) void mhar_kernel(
    const float* __restrict__ Q,
    const float* __restrict__ K,
    const float* __restrict__ V,
    const float* __restrict__ Qr,
    const float* __restrict__ Kr,
    float* __restrict__ out)
{
    const int b = blockIdx.x;
    const int t = threadIdx.x;

    __shared__ float  s_q[DIM];
    __shared__ float  s_sc[HEADS][88];   // scores then probs, padded
    __shared__ float4 s_red[8][32];      // phase-B partial sums

    // Stage Q row (128 floats) into LDS
    if (t < DIM) s_q[t] = Q[(size_t)b * DIM + t];
    __syncthreads();

    const int wave = t >> 6;   // one wave per head
    const int lane = t & 63;
    const int g    = lane >> 3;   // j-slot within wave (0..7)
    const int sub  = lane & 7;    // float4 index within 32-dim head chunk

    const float4* K4  = (const float4*)K;
    const float4* Kr4 = (const float4*)Kr;
    const float4* Qr4 = (const float4*)Qr;
    const float4* V4  = (const float4*)V;

    // ---- Phase A: scores s[h][j] = SCALE*( Q·(K+Kr) + Qr·K ) ----
    {
        const int h = wave;
        float4 q4 = ((const float4*)s_q)[h * 8 + sub];
        for (int jt = 0; jt < 11; ++jt) {
            int j = jt * 8 + g;
            if (j < J_LEN) {  // uniform across each 8-lane group
                size_t idx = ((size_t)b * J_LEN + j) * 32 + h * 8 + sub;
                float4 k  = K4[idx];
                float4 kr = Kr4[idx];
                float4 qr = Qr4[idx];
                float partial =
                      q4.x * (k.x + kr.x) + qr.x * k.x
                    + q4.y * (k.y + kr.y) + qr.y * k.y
                    + q4.z * (k.z + kr.z) + qr.z * k.z
                    + q4.w * (k.w + kr.w) + qr.w * k.w;
                partial += __shfl_xor(partial, 1);
                partial += __shfl_xor(partial, 2);
                partial += __shfl_xor(partial, 4);
                if (sub == 0) s_sc[h][j] = partial * SCALE;
            }
        }
    }
    __syncthreads();

    // ---- Phase A2: softmax over j per head (wave `wave` owns head `wave`) ----
    {
        float s0 = (lane < J_LEN)      ? s_sc[wave][lane]      : -INFINITY;
        float s1 = (lane + 64 < J_LEN) ? s_sc[wave][lane + 64] : -INFINITY;
        float m = fmaxf(s0, s1);
        #pragma unroll
        for (int off = 32; off > 0; off >>= 1)
            m = fmaxf(m, __shfl_xor(m, off));
        float e0 = (lane < J_LEN)      ? __expf(s0 - m) : 0.f;
        float e1 = (lane + 64 < J_LEN) ? __expf(s1 - m) : 0.f;
        float sum = e0 + e1;
        #pragma unroll
        for (int off = 32; off > 0; off >>= 1)
            sum += __shfl_xor(sum, off);
        float inv = 1.f / sum;
        if (lane < J_LEN)      s_sc[wave][lane]      = e0 * inv;
        if (lane + 64 < J_LEN) s_sc[wave][lane + 64] = e1 * inv;
    }
    __syncthreads();

    // ---- Phase B: out[h*32+d] = sum_j p[h][j] * V[b][j][h*32+d] ----
    {
        const int j_off = t >> 5;   // 0..7
        const int d4    = t & 31;   // float4 index across 128 dims
        const int h2    = d4 >> 3;  // head of this dim chunk
        float4 acc = {0.f, 0.f, 0.f, 0.f};
        for (int jt = 0; jt < 11; ++jt) {
            int j = jt * 8 + j_off;
            if (j < J_LEN) {
                float  p = s_sc[h2][j];
                float4 v = V4[((size_t)b * J_LEN + j) * 32 + d4];
                acc.x += p * v.x;
                acc.y += p * v.y;
                acc.z += p * v.z;
                acc.w += p * v.w;
            }
        }
        s_red[j_off][d4] = acc;
    }
    __syncthreads();

    if (t < 32) {
        float4 r = s_red[0][t];
        #pragma unroll
        for (int i = 1; i < 8; ++i) {
            float4 a = s_red[i][t];
            r.x += a.x; r.y += a.y; r.z += a.z; r.w += a.w;
        }
        ((float4*)out)[(size_t)b * 32 + t] = r;
    }
}

extern "C" void kernel_launch(void* const* d_in, const int* in_sizes, int n_in,
                              void* d_out, int out_size, void* d_ws, size_t ws_size,
                              hipStream_t stream) {
    const float* Q  = (const float*)d_in[0];
    const float* K  = (const float*)d_in[1];
    const float* V  = (const float*)d_in[2];
    const float* Qr = (const float*)d_in[3];
    const float* Kr = (const float*)d_in[4];
    float* out = (float*)d_out;
    const int B = in_sizes[0] / DIM;  // 8192
    mhar_kernel<<<B, 256, 0, stream>>>(Q, K, V, Qr, Kr, out);
}